// Round 15
// baseline (99.589 us; speedup 1.0000x reference)
//
#include <hip/hip_runtime.h>
#include <hip/hip_bf16.h>

// Round 15: algebraic fusion — P4 deleted. y = (sum_s e_s*g_s)/(sum_s e_s),
// g_s = sum_d x_i[d]*x_j[d]*fcw[d], computed from the SAME fp32 products that
// feed the bf16 B-frag pack (32 extra in-lane FMAs/tile). Removes: P4 MFMAs +
// its 96 ds_reads, Smh (6.9KB LDS) + zeroing + 780 scatters, one barrier.
// e and g stay fp32 (error should drop). Block = 128 thr = 2 waves on 1 row.

#define NF 40
#define ED 64
#define AS 32
#define NTILE 25
#define NSLOT 800
#define XS_STRIDE 68   // floats; 272B rows, 16B-aligned

typedef __attribute__((ext_vector_type(16))) float f32x16;
typedef __attribute__((ext_vector_type(8))) short bf16x8;

union ABFrag { bf16x8 v; unsigned int u[4]; uint4 q; };

// pack2: (bf16(a)) | (bf16(b) << 16) in 3 VALU; round-half-up (~RNE).
__device__ __forceinline__ unsigned int pack2(float a, float b) {
  unsigned int ua = __float_as_uint(a) + 0x8000u;
  unsigned int ub = __float_as_uint(b) + 0x8000u;
  return __builtin_amdgcn_perm(ub, ua, 0x07060302u);
}
// split: hi = pack2(a,b); lo = pack2 of the exact residuals.
__device__ __forceinline__ void split_pack(float a, float b,
                                           unsigned int& hi, unsigned int& lo) {
  hi = pack2(a, b);
  float ra = a - __uint_as_float(hi << 16);
  float rb = b - __uint_as_float(hi & 0xffff0000u);
  lo = pack2(ra, rb);
}

__global__ __launch_bounds__(128) void afm_kernel(
    const float* __restrict__ x, const float* __restrict__ attn_w,
    const float* __restrict__ attn_b, const float* __restrict__ proj_w,
    const float* __restrict__ proj_b, const float* __restrict__ fc_w,
    const float* __restrict__ fc_b, float* __restrict__ out) {
  __shared__ __align__(16) float xs[NF * XS_STRIDE];   // 10880 B
  __shared__ unsigned char pi_t[NSLOT], pj_t[NSLOT];   // 1600 B
  __shared__ float nums[2], dens[2];

  const int tid = threadIdx.x;
  const int lane = tid & 63;
  const int w = tid >> 6;            // wave id (0/1)
  const int half = lane >> 5;        // 32x32 MFMA k-half
  const int m32 = lane & 31;         // 32x32 MFMA row/col index
  const int row = blockIdx.x;
  const float* xg = x + row * (NF * ED);

  // ---- P1: stage x row (640 float4 over 128 threads) + pair tables.
#pragma unroll
  for (int v = 0; v < 5; ++v) {
    int e4 = v * 128 + tid;
    int f = e4 >> 4, c4 = e4 & 15;
    *(float4*)(xs + f * XS_STRIDE + c4 * 4) = *(const float4*)(xg + e4 * 4);
  }
  // Tiles 0..19: 4i x 8j rectangles fully above the diagonal
  //   (j0=1:ib 0-1, j0=2:ib 0-3, j0=3:ib 0-5, j0=4:ib 0-7).
  // Tiles 20..24: diagonal 8-chunks [8k,8k+8): 28 in-chunk pairs + 4 pads.
  for (int s = tid; s < NSLOT; s += 128) {
    int t = s >> 5, m = s & 31;
    int i = 0, j = 255;  // default: pad
    if (t < 20) {
      int j0, ib;
      if (t < 2) { j0 = 1; ib = t; }
      else if (t < 6) { j0 = 2; ib = t - 2; }
      else if (t < 12) { j0 = 3; ib = t - 6; }
      else { j0 = 4; ib = t - 12; }
      i = ib * 4 + (m >> 3);
      j = j0 * 8 + (m & 7);
    } else if (m < 28) {
      int k = t - 20;
      int mm = m, a = 0;
      while (mm >= 7 - a) { mm -= 7 - a; ++a; }  // triu of 8
      i = 8 * k + a;
      j = 8 * k + a + 1 + mm;
    }
    pi_t[s] = (unsigned char)i;
    pj_t[s] = (unsigned char)j;
  }

  // ---- per-lane constants (identical in both waves).
  // A-frag (32x32x16): A[mrow=m32][k=half*8+e]; A = W^T -> w[d][a=m32].
  ABFrag fwh[4], fwl[4];
#pragma unroll
  for (int s4 = 0; s4 < 4; ++s4)
#pragma unroll
    for (int p = 0; p < 4; ++p) {
      int d = s4 * 16 + half * 8 + 2 * p;
      split_pack(attn_w[d * AS + m32], attn_w[(d + 1) * AS + m32],
                 fwh[s4].u[p], fwl[s4].u[p]);
    }
  // Epilogue constants: C/D row(reg) = (reg&3) + 8*(reg>>2) + 4*half.
  float abv[16], pwv[16];
#pragma unroll
  for (int r = 0; r < 16; ++r) {
    int arow = (r & 3) + 8 * (r >> 2) + 4 * half;
    abv[r] = attn_b[arow];
    pwv[r] = proj_w[arow];
  }
  // fc_w values for this lane's 32 d-slots: d = s4*16 + half*8 + k.
  float fcv[4][8];
#pragma unroll
  for (int s4 = 0; s4 < 4; ++s4)
#pragma unroll
    for (int k = 0; k < 8; ++k)
      fcv[s4][k] = fc_w[s4 * 16 + half * 8 + k];
  const float fcb = fc_b[0];
  __syncthreads();  // B1: xs + tables ready (the only mid-kernel barrier)

  // ---- P2: wave w owns tiles [t0,t1). 32x32x16 MFMA (pairs on N) for
  // logits; g_s accumulated from the SAME fp32 products; fused
  // e = exp(logit), num += e*g, den += e. No max-subtract (|logit| << 88).
  const int t0 = w ? 13 : 0;
  const int t1 = w ? NTILE : 13;
  float num = 0.f, den = 0.f;
  for (int t = t0; t < t1; ++t) {
    const int slot = t * 32 + m32;
    const int fi = pi_t[slot];
    const int fjr = pj_t[slot];
    const bool pad = (fjr == 255);
    const int fj = pad ? 0 : fjr;
    const float* xi = xs + fi * XS_STRIDE + half * 8;
    const float* xj = xs + fj * XS_STRIDE + half * 8;
    f32x16 acc0, acc1;
#pragma unroll
    for (int r = 0; r < 16; ++r) { acc0[r] = abv[r]; acc1[r] = 0.f; }
    float g = 0.f;
#pragma unroll
    for (int s4 = 0; s4 < 4; ++s4) {
      float4 i0 = *(const float4*)(xi + s4 * 16);
      float4 i1 = *(const float4*)(xi + s4 * 16 + 4);
      float4 j0 = *(const float4*)(xj + s4 * 16);
      float4 j1 = *(const float4*)(xj + s4 * 16 + 4);
      float p0 = i0.x * j0.x, p1 = i0.y * j0.y;
      float p2 = i0.z * j0.z, p3 = i0.w * j0.w;
      float p4 = i1.x * j1.x, p5 = i1.y * j1.y;
      float p6 = i1.z * j1.z, p7 = i1.w * j1.w;
      ABFrag ip;  // B-frag: B[k=half*8+e][n=m32] = ip[pair][d]
      ip.u[0] = pack2(p0, p1);
      ip.u[1] = pack2(p2, p3);
      ip.u[2] = pack2(p4, p5);
      ip.u[3] = pack2(p6, p7);
      // g_s partial: fp32 products dotted with fc_w (in-register).
      g = fmaf(p0, fcv[s4][0], g); g = fmaf(p1, fcv[s4][1], g);
      g = fmaf(p2, fcv[s4][2], g); g = fmaf(p3, fcv[s4][3], g);
      g = fmaf(p4, fcv[s4][4], g); g = fmaf(p5, fcv[s4][5], g);
      g = fmaf(p6, fcv[s4][6], g); g = fmaf(p7, fcv[s4][7], g);
      if (s4 & 1) {  // two accumulator chains
        acc1 = __builtin_amdgcn_mfma_f32_32x32x16_bf16(fwh[s4].v, ip.v, acc1, 0, 0, 0);
        acc1 = __builtin_amdgcn_mfma_f32_32x32x16_bf16(fwl[s4].v, ip.v, acc1, 0, 0, 0);
      } else {
        acc0 = __builtin_amdgcn_mfma_f32_32x32x16_bf16(fwh[s4].v, ip.v, acc0, 0, 0, 0);
        acc0 = __builtin_amdgcn_mfma_f32_32x32x16_bf16(fwl[s4].v, ip.v, acc0, 0, 0, 0);
      }
    }
    float lg = 0.f;  // fused relu+proj (bias pre-folded into acc0)
#pragma unroll
    for (int r = 0; r < 16; ++r)
      lg = fmaf(fmaxf(acc0[r] + acc1[r], 0.f), pwv[r], lg);
    lg += __shfl_xor(lg, 32);  // combine a-halves -> full logit
    g += __shfl_xor(g, 32);    // combine d-halves -> full g_s
    if ((lane < 32) & !pad) {  // one lane-slot per pair
      float e = __expf(lg);
      den += e;
      num = fmaf(e, g, num);
    }
  }
  // 64-lane reduce (lanes >=32 carry zeros).
#pragma unroll
  for (int off = 1; off <= 32; off <<= 1) {
    num += __shfl_xor(num, off);
    den += __shfl_xor(den, off);
  }
  if (lane == 0) { nums[w] = num; dens[w] = den; }
  __syncthreads();  // B2: both waves' partials ready
  if (tid == 0)
    out[row] = (nums[0] + nums[1]) / (dens[0] + dens[1]) + fcb;
  (void)proj_b;  // cancels in softmax
}

extern "C" void kernel_launch(void* const* d_in, const int* in_sizes, int n_in,
                              void* d_out, int out_size, void* d_ws, size_t ws_size,
                              hipStream_t stream) {
  (void)in_sizes; (void)n_in; (void)out_size; (void)d_ws; (void)ws_size;
  afm_kernel<<<2048, 128, 0, stream>>>(
      (const float*)d_in[0], (const float*)d_in[1], (const float*)d_in[2],
      (const float*)d_in[3], (const float*)d_in[4], (const float*)d_in[5],
      (const float*)d_in[6], (float*)d_out);
}